// Round 9
// baseline (377.195 us; speedup 1.0000x reference)
//
#include <hip/hip_runtime.h>
#include <hip/hip_fp16.h>
#include <math.h>

#define N_NODES 50000
#define N_EDGES 800000
#define FEAT 128
#define EPS_W 1e-12f

// Q24 fixed-point packing: low 40 bits = sum of w*2^24, high 24 bits = count.
#define WSCALE 16777216.0f
#define MASK40 ((1ull << 40) - 1)

#define EDGE_BLOCKS 3125   // 800000 / 256
#define GEMM_BLOCKS 3125   // 50000 / 16
#define NBLK 49            // ceil(50000 / 1024) node-scan blocks
#define BINS 256

typedef unsigned long long u64;

// Session notes (measured):
//  r2: degree alone = 73 us (2 fabric atomics/edge, ~22 atomics/ns floor).
//  r7 FAILED: LDS-histogram degrees = 140+ us (8x edge re-read, occupancy 20%).
//  r8 FAILED: quarter-wave gather = +19 us (4-way row-length divergence).
//  r3-r8: GEMM fused into degree costs +27-36 us (not free); moved to fill.

// ---------- helpers ----------
__device__ __forceinline__ float selu_f(float x) {
  const float scale = 1.0507009873554805f;
  const float alpha = 1.6732632423543772f;
  return x > 0.f ? scale * x : scale * alpha * expm1f(x);
}

__device__ __forceinline__ float2 h2f2(unsigned int u) {
  __half2 h = *reinterpret_cast<__half2*>(&u);
  return __half22float2(h);
}

// ---------- 1. degree atomics + rank capture (pure; at the fabric floor) ------
__global__ __launch_bounds__(256) void degree_kernel(
    const int* __restrict__ src, const int* __restrict__ dst,
    const float* __restrict__ ew,
    u64* __restrict__ acc_out, u64* __restrict__ acc_in,
    unsigned short* __restrict__ rank) {
  int e = blockIdx.x * 256 + threadIdx.x;
  if (e >= N_EDGES) return;
  int s = src[e], d = dst[e];
  float w = ew[e];
  u64 p = (1ull << 40) | (u64)llrintf(w * WSCALE);
  atomicAdd(&acc_out[s], p);
  u64 old = atomicAdd(&acc_in[d], p);
  rank[e] = (unsigned short)(old >> 40);   // in-edge rank of e within row d
}

// ---------- 2. per-node inverse norms + rowptr partials + degree histogram -----
__global__ __launch_bounds__(256) void node_inv_scan(
    const u64* __restrict__ acc_out, const u64* __restrict__ acc_in,
    float* __restrict__ inv_out, float* __restrict__ inv_in,
    int* __restrict__ partials, int* __restrict__ lhist, int n) {
  __shared__ int sdata[256];
  __shared__ int hist[BINS];
  hist[threadIdx.x] = 0;
  __syncthreads();
  int base = blockIdx.x * 1024;
  int sum = 0;
  for (int j = 0; j < 4; ++j) {
    int i = base + j * 256 + threadIdx.x;
    if (i < n) {
      u64 po = acc_out[i], pi = acc_in[i];
      float wo = (float)(po & MASK40) * (1.0f / WSCALE);
      float wi = (float)(pi & MASK40) * (1.0f / WSCALE);
      float co = (float)(po >> 40);
      int ci = (int)(pi >> 40);
      inv_out[i] = (1.0f / sqrtf(fmaxf(wo, EPS_W))) * (1.0f / sqrtf(fmaxf(co, 1.0f)));
      inv_in[i]  = (1.0f / sqrtf(fmaxf(wi, EPS_W))) * (1.0f / sqrtf(fmaxf((float)ci, 1.0f)));
      sum += ci;
      atomicAdd(&hist[min(ci, BINS - 1)], 1);
    }
  }
  sdata[threadIdx.x] = sum;
  __syncthreads();
  for (int s = 128; s > 0; s >>= 1) {
    if (threadIdx.x < (unsigned)s) sdata[threadIdx.x] += sdata[threadIdx.x + s];
    __syncthreads();
  }
  if (threadIdx.x == 0) partials[blockIdx.x] = sdata[0];
  lhist[blockIdx.x * BINS + threadIdx.x] = hist[threadIdx.x];
}

__global__ void scan_small(int* __restrict__ partials, int nb) {
  int lane = threadIdx.x;  // launched with 64 threads, nb <= 64
  int v = (lane < nb) ? partials[lane] : 0;
  int incl = v;
#pragma unroll
  for (int off = 1; off < 64; off <<= 1) {
    int tv = __shfl_up(incl, off);
    if (lane >= off) incl += tv;
  }
  if (lane < nb) partials[lane] = incl - v;  // exclusive
}

// ---------- 2b. scan the 49x256 degree histogram (bin-major) -> lbase ----------
__global__ __launch_bounds__(256) void scan_bins(
    const int* __restrict__ lhist, int* __restrict__ lbase) {
  __shared__ int bsum[BINS];
  int d = threadIdx.x;
  int run = 0;
  for (int b = 0; b < NBLK; ++b) {
    lbase[b * BINS + d] = run;            // exclusive within bin d
    run += lhist[b * BINS + d];
  }
  bsum[d] = run;
  __syncthreads();
  for (int off = 1; off < BINS; off <<= 1) {
    int v = (d >= off) ? bsum[d - off] : 0;
    __syncthreads();
    bsum[d] += v;
    __syncthreads();
  }
  int binbase = bsum[d] - run;            // exclusive across bins
  for (int b = 0; b < NBLK; ++b) lbase[b * BINS + d] += binbase;
}

// ---------- 3. rowptr scan-write + degree-sorted row permutation ----------
__global__ __launch_bounds__(256) void scan_write_perm(
    const u64* __restrict__ acc_in, const int* __restrict__ partials,
    const int* __restrict__ lbase, int* __restrict__ rowptr,
    int* __restrict__ perm, int n) {
  __shared__ int sh[256];
  __shared__ int cnt[BINS];
  cnt[threadIdx.x] = 0;
  int t = threadIdx.x;
  int base = blockIdx.x * 1024;
  int c[4], local[4], s = 0;
#pragma unroll
  for (int j = 0; j < 4; ++j) {
    int i = base + t * 4 + j;
    c[j] = (i < n) ? (int)(acc_in[i] >> 40) : 0;
    s += c[j];
    local[j] = s;  // inclusive within thread
  }
  sh[t] = s;
  __syncthreads();
  for (int off = 1; off < 256; off <<= 1) {
    int v = (t >= off) ? sh[t - off] : 0;
    __syncthreads();
    sh[t] += v;
    __syncthreads();
  }
  int thread_excl = sh[t] - s;
  int pbase = partials[blockIdx.x];
#pragma unroll
  for (int j = 0; j < 4; ++j) {
    int i = base + t * 4 + j;
    if (i < n) {
      int excl = pbase + thread_excl + local[j] - c[j];
      rowptr[i] = excl;
      if (i == n - 1) rowptr[n] = excl + c[j];
      // degree-sorted permutation: slot = bin base + LDS-atomic local rank
      int d = min(c[j], BINS - 1);
      int r = atomicAdd(&cnt[d], 1);
      perm[lbase[blockIdx.x * BINS + d] + r] = i;
    }
  }
}

// ---------- GEMM body: 16 rows of A (n x 128) @ W (128 x 128) -> fp16 out ------
__device__ __forceinline__ void gemm16_half_body(
    const float* __restrict__ A, const float* __restrict__ W,
    __half* __restrict__ out, int row0, int n, float* aL /*16*128 LDS*/) {
  for (int i = threadIdx.x; i < 16 * 128; i += 256) {
    int r = row0 + (i >> 7);
    aL[i] = (r < n) ? A[row0 * 128 + i] : 0.f;
  }
  __syncthreads();
  int col = threadIdx.x & 63;
  int rg = threadIdx.x >> 6;  // 0..3
  float acc[4][2] = {};
  const float4* a4 = (const float4*)&aL[rg * 4 * 128];
#pragma unroll 8
  for (int k4 = 0; k4 < 32; ++k4) {
    float w0 = W[(4 * k4 + 0) * 128 + col];
    float w1 = W[(4 * k4 + 1) * 128 + col];
    float w2 = W[(4 * k4 + 2) * 128 + col];
    float w3 = W[(4 * k4 + 3) * 128 + col];
    float e0 = W[(4 * k4 + 0) * 128 + col + 64];
    float e1 = W[(4 * k4 + 1) * 128 + col + 64];
    float e2 = W[(4 * k4 + 2) * 128 + col + 64];
    float e3 = W[(4 * k4 + 3) * 128 + col + 64];
#pragma unroll
    for (int r = 0; r < 4; ++r) {
      float4 a = a4[r * 32 + k4];
      acc[r][0] += a.x * w0 + a.y * w1 + a.z * w2 + a.w * w3;
      acc[r][1] += a.x * e0 + a.y * e1 + a.z * e2 + a.w * e3;
    }
  }
#pragma unroll
  for (int r = 0; r < 4; ++r) {
    int row = row0 + rg * 4 + r;
    if (row < n) {
      out[(size_t)row * 128 + col]      = __float2half_rn(acc[r][0]);
      out[(size_t)row * 128 + col + 64] = __float2half_rn(acc[r][1]);
    }
  }
}

// ---------- 4. FUSED: atomic-free CSR fill (odd blocks) || x@W1 (even) ---------
// fill is scatter/latency-bound with VALU idle -> the GEMM co-schedules here
// (cheaper than under the degree atomics, r3-r8 showed +27-36us there).
__global__ __launch_bounds__(256) void fill_gemm(
    const int* __restrict__ src, const int* __restrict__ dst,
    const float* __restrict__ ew,
    const float* __restrict__ inv_out, const float* __restrict__ inv_in,
    const int* __restrict__ rowptr, const unsigned short* __restrict__ rank,
    int2* __restrict__ edges,
    const float* __restrict__ x, const float* __restrict__ W1,
    __half* __restrict__ bufG) {
  __shared__ float aL[16 * 128];
  if (blockIdx.x & 1) {
    int e = (blockIdx.x >> 1) * 256 + threadIdx.x;
    if (e >= N_EDGES) return;
    int s = src[e], d = dst[e];
    float c = ew[e] * inv_out[s] * inv_in[d];
    int pos = rowptr[d] + (int)rank[e];
    int2 rec; rec.x = s; rec.y = __float_as_int(c);
    edges[pos] = rec;  // single 8B scattered store, no atomic
  } else {
    int row0 = (blockIdx.x >> 1) * 16;
    gemm16_half_body(x, W1, bufG, row0, N_NODES, aL);
  }
}

// ---------- half-wave gather: 32 lanes cover a 128-wide fp16 row (r6 proven) ---
__device__ __forceinline__ float4 gather_row_half(
    const int* __restrict__ rowptr, const int2* __restrict__ edges,
    const uint2* __restrict__ xh /* row stride 32 */, int row, int sub) {
  int beg = rowptr[row], end = rowptr[row + 1];
  float4 acc = make_float4(0.f, 0.f, 0.f, 0.f);
  int e = beg;
  for (; e + 7 < end; e += 8) {
    int2 p0 = edges[e + 0], p1 = edges[e + 1], p2 = edges[e + 2], p3 = edges[e + 3];
    int2 p4 = edges[e + 4], p5 = edges[e + 5], p6 = edges[e + 6], p7 = edges[e + 7];
    uint2 q0 = xh[(size_t)p0.x * 32 + sub];
    uint2 q1 = xh[(size_t)p1.x * 32 + sub];
    uint2 q2 = xh[(size_t)p2.x * 32 + sub];
    uint2 q3 = xh[(size_t)p3.x * 32 + sub];
    uint2 q4 = xh[(size_t)p4.x * 32 + sub];
    uint2 q5 = xh[(size_t)p5.x * 32 + sub];
    uint2 q6 = xh[(size_t)p6.x * 32 + sub];
    uint2 q7 = xh[(size_t)p7.x * 32 + sub];
#define ACC_EDGE(P, Q)                                              \
    {                                                               \
      float cc = __int_as_float(P.y);                               \
      float2 lo = h2f2(Q.x);                                        \
      float2 hi = h2f2(Q.y);                                        \
      acc.x += cc * lo.x; acc.y += cc * lo.y;                       \
      acc.z += cc * hi.x; acc.w += cc * hi.y;                       \
    }
    ACC_EDGE(p0, q0) ACC_EDGE(p1, q1) ACC_EDGE(p2, q2) ACC_EDGE(p3, q3)
    ACC_EDGE(p4, q4) ACC_EDGE(p5, q5) ACC_EDGE(p6, q6) ACC_EDGE(p7, q7)
  }
  for (; e < end; ++e) {
    int2 p0 = edges[e];
    uint2 q0 = xh[(size_t)p0.x * 32 + sub];
    ACC_EDGE(p0, q0)
  }
#undef ACC_EDGE
  return acc;
}

// ---------- 5a. layer-1: spmm + bias + selu + fused @W2, degree-sorted rows ----
// 8 rows/block via perm: all 8 rows have ~equal degree -> minimal divergence
// and barrier idle. lo half-wave: cols 0..63, hi: 64..127.
__global__ __launch_bounds__(256) void spmm_selu_gemm(
    const int* __restrict__ rowptr, const int2* __restrict__ edges,
    const uint2* __restrict__ g, const float* __restrict__ bias,
    const float* __restrict__ W, __half* __restrict__ out,
    const int* __restrict__ perm, int n) {
  __shared__ float hL[8 * 128];
  __shared__ int prow[8];
  int wid = threadIdx.x >> 6, lane = threadIdx.x & 63;
  int half = lane >> 5, sub = lane & 31;
  int lrow = wid * 2 + half;                 // 0..7 within block
  int row = perm[blockIdx.x * 8 + lrow];     // grid exact
  if (sub == 0) prow[lrow] = row;
  float4 a = gather_row_half(rowptr, edges, g, row, sub);
  float4 b = ((const float4*)bias)[sub];
  float4 h;
  h.x = selu_f(a.x + b.x);
  h.y = selu_f(a.y + b.y);
  h.z = selu_f(a.z + b.z);
  h.w = selu_f(a.w + b.w);
  ((float4*)hL)[lrow * 32 + sub] = h;
  __syncthreads();
  int col = threadIdx.x & 127;
  int rq = threadIdx.x >> 7;
  const float4* h4 = (const float4*)&hL[rq * 4 * 128];
  float acc0 = 0.f, acc1 = 0.f, acc2 = 0.f, acc3 = 0.f;
#pragma unroll 8
  for (int k4 = 0; k4 < 32; ++k4) {
    float w0 = W[(4 * k4 + 0) * 128 + col];
    float w1 = W[(4 * k4 + 1) * 128 + col];
    float w2 = W[(4 * k4 + 2) * 128 + col];
    float w3 = W[(4 * k4 + 3) * 128 + col];
    float4 h0 = h4[0 * 32 + k4];             // broadcast ds_read_b128
    float4 h1 = h4[1 * 32 + k4];
    float4 h2 = h4[2 * 32 + k4];
    float4 h3 = h4[3 * 32 + k4];
    acc0 += h0.x * w0 + h0.y * w1 + h0.z * w2 + h0.w * w3;
    acc1 += h1.x * w0 + h1.y * w1 + h1.z * w2 + h1.w * w3;
    acc2 += h2.x * w0 + h2.y * w1 + h2.z * w2 + h2.w * w3;
    acc3 += h3.x * w0 + h3.y * w1 + h3.z * w2 + h3.w * w3;
  }
  int lr0 = rq * 4;
  out[(size_t)prow[lr0 + 0] * 128 + col] = __float2half_rn(acc0);
  out[(size_t)prow[lr0 + 1] * 128 + col] = __float2half_rn(acc1);
  out[(size_t)prow[lr0 + 2] * 128 + col] = __float2half_rn(acc2);
  out[(size_t)prow[lr0 + 3] * 128 + col] = __float2half_rn(acc3);
}

// ---------- 5b. layer-2: spmm + bias + selu -> fp32 output, sorted rows --------
__global__ __launch_bounds__(256) void spmm_ep(
    const int* __restrict__ rowptr, const int2* __restrict__ edges,
    const uint2* __restrict__ xh, const float* __restrict__ bias,
    float* __restrict__ out, const int* __restrict__ perm, int n) {
  int wid = threadIdx.x >> 6, lane = threadIdx.x & 63;
  int half = lane >> 5, sub = lane & 31;
  int row = perm[blockIdx.x * 8 + wid * 2 + half];   // grid exact
  float4 a = gather_row_half(rowptr, edges, xh, row, sub);
  float4 b = ((const float4*)bias)[sub];
  float4 r;
  r.x = selu_f(a.x + b.x);
  r.y = selu_f(a.y + b.y);
  r.z = selu_f(a.z + b.z);
  r.w = selu_f(a.w + b.w);
  ((float4*)out)[(size_t)row * 32 + sub] = r;
}

extern "C" void kernel_launch(void* const* d_in, const int* in_sizes, int n_in,
                              void* d_out, int out_size, void* d_ws, size_t ws_size,
                              hipStream_t stream) {
  const float* x   = (const float*)d_in[0];
  const int*   src = (const int*)d_in[1];
  const int*   dst = (const int*)d_in[2];
  const float* ew  = (const float*)d_in[3];
  const float* W1  = (const float*)d_in[4];
  const float* b1  = (const float*)d_in[5];
  const float* W2  = (const float*)d_in[6];
  const float* b2  = (const float*)d_in[7];
  float* out = (float*)d_out;

  // workspace layout (byte offsets; 8B for u64/int2, 16B for edges & fp16 bufs)
  char* ws = (char*)d_ws;
  u64*   acc_out  = (u64*)(ws + 0);             //   400,000 B
  u64*   acc_in   = (u64*)(ws + 400000);        //   400,000 B
  float* inv_out  = (float*)(ws + 800000);      //   200,000 B
  float* inv_in   = (float*)(ws + 1000000);     //   200,000 B
  int*   rowptr   = (int*)(ws + 1200000);       //   200,004 B
  int*   partials = (int*)(ws + 1400004);       //       256 B
  int*   lhist    = (int*)(ws + 1400260);       //    50,176 B
  int*   lbase    = (int*)(ws + 1450436);       //    50,176 B
  int*   perm     = (int*)(ws + 1500612);       //   200,000 B
  unsigned short* rank = (unsigned short*)(ws + 1700612);  // 1,600,000 B
  int2*  edges    = (int2*)(ws + 3300624);      // 6,400,000 B (16B aligned)
  __half* bufG    = (__half*)(ws + 9700624);    // 12,800,000 B (fp16)
  __half* bufB    = (__half*)(ws + 22500624);   // 12,800,000 B (fp16)

  // zero the two packed degree accumulators
  hipMemsetAsync(d_ws, 0, (size_t)(2 * N_NODES) * sizeof(u64), stream);

  // 1. degree atomics + rank capture (fabric-atomic floor, ~73us)
  degree_kernel<<<EDGE_BLOCKS, 256, 0, stream>>>(src, dst, ew, acc_out, acc_in, rank);
  // 2. norms + rowptr partials + degree histogram
  node_inv_scan<<<NBLK, 256, 0, stream>>>(acc_out, acc_in, inv_out, inv_in,
                                          partials, lhist, N_NODES);
  scan_small<<<1, 64, 0, stream>>>(partials, NBLK);
  scan_bins<<<1, BINS, 0, stream>>>(lhist, lbase);
  // 3. rowptr + degree-sorted row permutation
  scan_write_perm<<<NBLK, 256, 0, stream>>>(acc_in, partials, lbase, rowptr,
                                            perm, N_NODES);
  // 4. atomic-free CSR fill || bufG = fp16(x @ W1)
  fill_gemm<<<EDGE_BLOCKS + GEMM_BLOCKS, 256, 0, stream>>>(
      src, dst, ew, inv_out, inv_in, rowptr, rank, edges, x, W1, bufG);

  const int RB8 = N_NODES / 8;                  // 6250 (8 rows / block, exact)

  // layer 1 + layer-2 GEMM: bufB = fp16( selu(A_hat·(x@W1) + b1) @ W2 )
  spmm_selu_gemm<<<RB8, 256, 0, stream>>>(rowptr, edges, (const uint2*)bufG,
                                          b1, W2, bufB, perm, N_NODES);
  // layer 2: out = selu(A_hat·bufB + b2)
  spmm_ep<<<RB8, 256, 0, stream>>>(rowptr, edges, (const uint2*)bufB, b2,
                                   out, perm, N_NODES);
}